// Round 6
// baseline (84.734 us; speedup 1.0000x reference)
//
#include <hip/hip_runtime.h>

// 8-qubit batched statevector sim, v6: full wave occupancy.
//   32 lanes per element (s5 = lane&31), 8 float2 regs per lane, 2 elems/wave.
//   2048 blocks x 256 thr = 8192 waves = 8 waves/SIMD (100% of 32 waves/CU).
// amp idx = s5*8 + r.  idx bit p: p<3 -> r bit p ; p>=3 -> s5 bit (p-3).
// qubit q <-> idx bit (7-q):  q0..q4 -> s5 bits 4..0 ; q5..q7 -> r bits 2..0.
// Cross-lane: xor1/2 quad_perm, xor4 half_mirror+quad, xor8 row_ror:8 (DPP),
// xor16 ds_swizzle BitMode 0x401F (32-lane groups == element boundary).

static __device__ __forceinline__ float rlane(float v, int src) {
    return __int_as_float(__builtin_amdgcn_readlane(__float_as_int(v), src));
}
template <int CTRL>
static __device__ __forceinline__ float dppf(float x) {
    return __int_as_float(__builtin_amdgcn_update_dpp(0, __float_as_int(x), CTRL, 0xF, 0xF, true));
}
static __device__ __forceinline__ float xor1f(float x)  { return dppf<0xB1>(x); }
static __device__ __forceinline__ float xor2f(float x)  { return dppf<0x4E>(x); }
static __device__ __forceinline__ float xor4f(float x)  { return dppf<0x1B>(dppf<0x141>(x)); }
static __device__ __forceinline__ float xor8f(float x)  { return dppf<0x128>(x); }
static __device__ __forceinline__ float xor16f(float x) {
    return __int_as_float(__builtin_amdgcn_ds_swizzle(__float_as_int(x), 0x401F));
}
static __device__ __forceinline__ float xorMf(float x, int m) {  // m const after unroll
    if (m == 1)  return xor1f(x);
    if (m == 2)  return xor2f(x);
    if (m == 4)  return xor4f(x);
    if (m == 8)  return xor8f(x);
    return xor16f(x);
}
static __device__ __forceinline__ float2 xorM2(float2 a, int m) {
    float2 t; t.x = xorMf(a.x, m); t.y = xorMf(a.y, m); return t;
}
static __device__ __forceinline__ float2 cmul(float2 a, float2 b) {
    float2 t;
    t.x = a.x * b.x - a.y * b.y;
    t.y = a.x * b.y + a.y * b.x;
    return t;
}
// CRX half-rotation: c*t - i*s*u  ->  (c*t.x + s*u.y, c*t.y - s*u.x)
static __device__ __forceinline__ float2 rotA(float2 t, float2 u, float c, float s) {
    float2 d;
    d.x = c * t.x + s * u.y;
    d.y = c * t.y - s * u.x;
    return d;
}

__global__ __launch_bounds__(256, 8) void qsim_kernel(const float* __restrict__ X,
                                                      const float* __restrict__ W,
                                                      float* __restrict__ out,
                                                      int B) {
    const int lane = threadIdx.x & 63;
    const int e  = lane >> 5;   // element slot in wave (0,1)
    const int s5 = lane & 31;   // sublane within element
    const int b = (blockIdx.x * 4 + (threadIdx.x >> 6)) * 2 + e;
    const bool active = (b < B);
    const int bc = active ? b : (B - 1);   // clamp loads; keep all lanes alive for DPP

    // ---- CRX trig: lane gi (<56) holds cos/sin of 0.5*W[1+i, j] (wave-shared) ----
    float gcv = 1.0f, gsv = 0.0f;
    if (lane < 56) {
        const int i = lane / 7;
        const int jj = lane - 7 * i;
        const int j = jj + (jj >= i ? 1 : 0);
        const float h = 0.5f * W[(1 + i) * 72 + j];
        __sincosf(h, &gsv, &gcv);
    }

    // ---- per-qubit fused H->RZ->RY first column (sublane q computes qubit q) ----
    float u0r, u0i, u1r, u1i;
    {
        const int q = s5 & 7;
        float2 xq = ((const float2*)X)[bc * 8 + q];
        float cz, sz, cy, sy;
        __sincosf(0.5f * xq.x, &sz, &cz);
        __sincosf(0.5f * xq.y, &sy, &cy);
        u0r = (cy - sy) * cz;  u0i = -(cy + sy) * sz;
        u1r = (cy + sy) * cz;  u1i = (cy - sy) * sz;
    }

    // ---- product state ----
    // lane part: qubits 0..4 -> s5 bits 4..0
    float2 P; P.x = 1.0f; P.y = 0.0f;
#pragma unroll
    for (int q = 0; q < 5; ++q) {
        const int src = (e << 5) + q;
        const float a0r = __shfl(u0r, src, 64), a0i = __shfl(u0i, src, 64);
        const float a1r = __shfl(u1r, src, 64), a1i = __shfl(u1i, src, 64);
        const int bit = (s5 >> (4 - q)) & 1;
        float2 v; v.x = bit ? a1r : a0r; v.y = bit ? a1i : a0i;
        P = cmul(P, v);
    }
    // reg part: qubits 5,6,7 -> r bits 2,1,0
    float2 w0[3], w1[3];
#pragma unroll
    for (int k = 0; k < 3; ++k) {
        const int src = (e << 5) + 5 + k;
        w0[k].x = __shfl(u0r, src, 64);  w0[k].y = __shfl(u0i, src, 64);
        w1[k].x = __shfl(u1r, src, 64);  w1[k].y = __shfl(u1i, src, 64);
    }
    float2 a[8];
    {
        float2 t1[2];                       // r bit2 (qubit5)
        t1[0] = w0[0];
        t1[1] = w1[0];
        float2 t2[4];                       // (b2<<1)|b1 (qubit6)
#pragma unroll
        for (int h = 0; h < 2; ++h) {
            t2[h * 2 + 0] = cmul(t1[h], w0[1]);
            t2[h * 2 + 1] = cmul(t1[h], w1[1]);
        }
#pragma unroll
        for (int h = 0; h < 4; ++h) {       // b0 (qubit7), then fold P
            a[h * 2 + 0] = cmul(P, cmul(t2[h], w0[2]));
            a[h * 2 + 1] = cmul(P, cmul(t2[h], w1[2]));
        }
    }

    // ---- CRZ ring fused into one diagonal phase per amp ----
    // idx-bit pairs (ctrl,tgt,w): (7,6,w0)(6,5,w1)(5,4,w2)(4,3,w3)(3,2,w4)(2,1,w5)(1,0,w6)(0,7,w7)
    // bits 7..3 = s5 bits 4..0 ; bits 2..0 = r bits 2..0.
    {
        const float wv0 = W[0], wv1 = W[1], wv2 = W[2], wv3 = W[3];
        const float wv4 = W[4], wv5 = W[5], wv6 = W[6], wv7 = W[7];
        const int s4b = (s5 >> 4) & 1, s3b = (s5 >> 3) & 1, s2b = (s5 >> 2) & 1;
        const int s1b = (s5 >> 1) & 1, s0b = s5 & 1;
        float phiS = 0.0f;
        phiS += s4b ? (s3b ? wv0 : -wv0) : 0.0f;
        phiS += s3b ? (s2b ? wv1 : -wv1) : 0.0f;
        phiS += s2b ? (s1b ? wv2 : -wv2) : 0.0f;
        phiS += s1b ? (s0b ? wv3 : -wv3) : 0.0f;
        const float termA = s0b ? wv4 : 0.0f;   // pair (3,2): ctrl s5b0, sign by r bit2
        const float termB = s4b ? wv7 : -wv7;   // pair (0,7): ctrl r bit0, sign by s5b4
#pragma unroll
        for (int r = 0; r < 8; ++r) {
            const int b2 = (r >> 2) & 1, b1 = (r >> 1) & 1, b0 = r & 1;
            float phi = phiS + (b2 ? termA : -termA);
            if (b2) phi += b1 ? wv5 : -wv5;
            if (b1) phi += b0 ? wv6 : -wv6;
            if (b0) phi += termB;
            float2 ph;
            __sincosf(0.5f * phi, &ph.y, &ph.x);
            a[r] = cmul(a[r], ph);
        }
    }

    // ---- 56 CRX gates in reference order ----
    // ctrl qubit i: i<=4 -> s5 bit (4-i) [fold into coeffs]; i>=5 -> r bit (7-i) [half work].
    // tgt qubit j:  j<=4 -> lane xor 1<<(4-j); j>=5 -> r bit (7-j).
#pragma unroll
    for (int i = 0; i < 8; ++i) {
        float cg[8], sg[8];
#pragma unroll
        for (int j = 0; j < 8; ++j) {
            if (j == i) continue;
            const int gi = i * 7 + (j < i ? j : j - 1);
            cg[j] = rlane(gcv, gi);
            sg[j] = rlane(gsv, gi);
        }
        if (i <= 4) {
            const int cbit = (s5 >> (4 - i)) & 1;
#pragma unroll
            for (int j = 0; j < 8; ++j) {
                if (j == i) continue;
                const float ce = cbit ? cg[j] : 1.0f;
                const float se = cbit ? sg[j] : 0.0f;
                if (j <= 4) {   // lane target
                    const int ms = 1 << (4 - j);
#pragma unroll
                    for (int r = 0; r < 8; ++r) {
                        const float2 p = xorM2(a[r], ms);
                        a[r] = rotA(a[r], p, ce, se);
                    }
                } else {        // reg target
                    const int mt = 1 << (7 - j);
#pragma unroll
                    for (int r = 0; r < 8; ++r) {
                        if (r & mt) continue;
                        const int rp = r | mt;
                        const float2 t = a[r], u = a[rp];
                        a[r]  = rotA(t, u, ce, se);
                        a[rp] = rotA(u, t, ce, se);
                    }
                }
            }
        } else {
            const int rc = 7 - i;   // ctrl reg bit
#pragma unroll
            for (int j = 0; j < 8; ++j) {
                if (j == i) continue;
                if (j <= 4) {   // lane target, only ctrl=1 regs
                    const int ms = 1 << (4 - j);
#pragma unroll
                    for (int r = 0; r < 8; ++r) {
                        if (!((r >> rc) & 1)) continue;
                        const float2 p = xorM2(a[r], ms);
                        a[r] = rotA(a[r], p, cg[j], sg[j]);
                    }
                } else {        // reg target, only ctrl=1 pairs
                    const int mt = 1 << (7 - j);
#pragma unroll
                    for (int r = 0; r < 8; ++r) {
                        if (!((r >> rc) & 1)) continue;
                        if (r & mt) continue;
                        const int rp = r | mt;
                        const float2 t = a[r], u = a[rp];
                        a[r]  = rotA(t, u, cg[j], sg[j]);
                        a[rp] = rotA(u, t, cg[j], sg[j]);
                    }
                }
            }
        }
    }

    // ---- probabilities + all 8 <Z_q> ----
    float p[8];
#pragma unroll
    for (int r = 0; r < 8; ++r) p[r] = a[r].x * a[r].x + a[r].y * a[r].y;
    // in-reg tree: r bit0 -> q7, bit1 -> q6, bit2 -> q5
    float s4v[4], E7 = 0.0f;
#pragma unroll
    for (int k = 0; k < 4; ++k) { s4v[k] = p[2 * k] + p[2 * k + 1]; E7 += p[2 * k] - p[2 * k + 1]; }
    float s2v[2], E6 = 0.0f;
#pragma unroll
    for (int k = 0; k < 2; ++k) { s2v[k] = s4v[2 * k] + s4v[2 * k + 1]; E6 += s4v[2 * k] - s4v[2 * k + 1]; }
    float A  = s2v[0] + s2v[1];
    float E5 = s2v[0] - s2v[1];
    // cross-lane signed butterfly over s5 bits k (qubit 4-k)
    float D0, D1, D2, D3, D4;
    { const float t = xor1f(A);  D0 = A - t; A += t;
      E5 += xor1f(E5);  E6 += xor1f(E6);  E7 += xor1f(E7); }
    { const float t = xor2f(A);  D1 = A - t; A += t;
      D0 += xor2f(D0);
      E5 += xor2f(E5);  E6 += xor2f(E6);  E7 += xor2f(E7); }
    { const float t = xor4f(A);  D2 = A - t; A += t;
      D0 += xor4f(D0);  D1 += xor4f(D1);
      E5 += xor4f(E5);  E6 += xor4f(E6);  E7 += xor4f(E7); }
    { const float t = xor8f(A);  D3 = A - t; A += t;
      D0 += xor8f(D0);  D1 += xor8f(D1);  D2 += xor8f(D2);
      E5 += xor8f(E5);  E6 += xor8f(E6);  E7 += xor8f(E7); }
    { const float t = xor16f(A); D4 = A - t;
      D0 += xor16f(D0); D1 += xor16f(D1); D2 += xor16f(D2); D3 += xor16f(D3);
      E5 += xor16f(E5); E6 += xor16f(E6); E7 += xor16f(E7); }

    if (s5 == 0 && active) {
        const float sc = 1.0f / 256.0f;  // (1/sqrt2)^8 squared, folded out of u's
        float* o = out + b * 8;
        o[0] = D4 * sc;  // qubit0 <- s5 bit4
        o[1] = D3 * sc;  // qubit1 <- s5 bit3
        o[2] = D2 * sc;
        o[3] = D1 * sc;
        o[4] = D0 * sc;  // qubit4 <- s5 bit0
        o[5] = E5 * sc;  // qubit5 <- r bit2
        o[6] = E6 * sc;
        o[7] = E7 * sc;
    }
}

extern "C" void kernel_launch(void* const* d_in, const int* in_sizes, int n_in,
                              void* d_out, int out_size, void* d_ws, size_t ws_size,
                              hipStream_t stream) {
    const float* X = (const float*)d_in[0];
    const float* W = (const float*)d_in[1];
    float* out = (float*)d_out;
    const int B = in_sizes[0] / 16;       // 2*N floats per row
    const int blocks = (B + 7) / 8;       // 4 waves x 2 elements per 256-thread block
    qsim_kernel<<<blocks, 256, 0, stream>>>(X, W, out, B);
}

// Round 7
// 76.404 us; speedup vs baseline: 1.1090x; 1.1090x over previous
//
#include <hip/hip_runtime.h>

// 8-qubit batched statevector sim, v7: v5 body, repartitioned grid.
//   16 lanes per element (sublane s = lane&15), 16 float2 regs per lane, 4 elems/wave.
//   256 blocks x 1024 threads = 4096 waves (same as v5) but 4x fewer workgroups:
//   tests command-processor dispatch serialization (~10ns/block ramp).
// Phase A layout L1: amp idx = r*16 + s ; qubits 0..3 -> r bits 3..0, 4..7 -> s bits 3..0.
// Then 16x16 DPP xor-swap transpose to L2: amp idx = s*16 + r ; groups i=4..7 reg-ctrl.
// All cross-lane via DPP: xor1=quad_perm[1,0,3,2], xor2=quad_perm[2,3,0,1],
// xor4=half_mirror o quad_perm[3,2,1,0], xor8=row_ror:8.

static __device__ __forceinline__ float rlane(float v, int src) {
    return __int_as_float(__builtin_amdgcn_readlane(__float_as_int(v), src));
}
template <int CTRL>
static __device__ __forceinline__ float dppf(float x) {
    return __int_as_float(__builtin_amdgcn_update_dpp(0, __float_as_int(x), CTRL, 0xF, 0xF, true));
}
static __device__ __forceinline__ float xor1f(float x) { return dppf<0xB1>(x); }
static __device__ __forceinline__ float xor2f(float x) { return dppf<0x4E>(x); }
static __device__ __forceinline__ float xor4f(float x) { return dppf<0x1B>(dppf<0x141>(x)); }
static __device__ __forceinline__ float xor8f(float x) { return dppf<0x128>(x); }
static __device__ __forceinline__ float xorMf(float x, int m) {  // m compile-time after unroll
    if (m == 1) return xor1f(x);
    if (m == 2) return xor2f(x);
    if (m == 4) return xor4f(x);
    return xor8f(x);
}
static __device__ __forceinline__ float2 xorM2(float2 a, int m) {
    float2 t; t.x = xorMf(a.x, m); t.y = xorMf(a.y, m); return t;
}
static __device__ __forceinline__ float2 cmul(float2 a, float2 b) {
    float2 t;
    t.x = a.x * b.x - a.y * b.y;
    t.y = a.x * b.y + a.y * b.x;
    return t;
}
// CRX half-rotation: c*t - i*s*u  ->  (c*t.x + s*u.y, c*t.y - s*u.x)
static __device__ __forceinline__ float2 rotA(float2 t, float2 u, float c, float s) {
    float2 d;
    d.x = c * t.x + s * u.y;
    d.y = c * t.y - s * u.x;
    return d;
}

__global__ __launch_bounds__(1024, 4) void qsim_kernel(const float* __restrict__ X,
                                                       const float* __restrict__ W,
                                                       float* __restrict__ out,
                                                       int B) {
    const int lane = threadIdx.x & 63;
    const int warp = threadIdx.x >> 6;   // 0..15
    const int g = lane >> 4;   // element slot in wave
    const int s = lane & 15;   // sublane within element
    const int b = (blockIdx.x * 16 + warp) * 4 + g;
    const bool active = (b < B);
    const int bc = active ? b : (B - 1);   // clamp loads; keep all lanes alive for DPP

    // ---- CRX trig: lane gi (<56) holds cos/sin of 0.5*W[1+i, j] (wave-shared) ----
    float gcv = 1.0f, gsv = 0.0f;
    if (lane < 56) {
        const int i = lane / 7;
        const int jj = lane - 7 * i;
        const int j = jj + (jj >= i ? 1 : 0);
        const float h = 0.5f * W[(1 + i) * 72 + j];
        __sincosf(h, &gsv, &gcv);
    }

    // ---- per-qubit fused H->RZ->RY first column (sublane q computes qubit q) ----
    float u0r, u0i, u1r, u1i;
    {
        const int q = s & 7;
        float2 xq = ((const float2*)X)[bc * 8 + q];
        float cz, sz, cy, sy;
        __sincosf(0.5f * xq.x, &sz, &cz);
        __sincosf(0.5f * xq.y, &sy, &cy);
        u0r = (cy - sy) * cz;  u0i = -(cy + sy) * sz;
        u1r = (cy + sy) * cz;  u1i = (cy - sy) * sz;
    }

    // ---- product state in L1 ----
    // lane part: qubits 4..7 -> s bits 3..0
    float2 P; P.x = 1.0f; P.y = 0.0f;
#pragma unroll
    for (int q = 4; q < 8; ++q) {
        const int src = (g << 4) + q;
        const float a0r = __shfl(u0r, src, 64), a0i = __shfl(u0i, src, 64);
        const float a1r = __shfl(u1r, src, 64), a1i = __shfl(u1i, src, 64);
        const int bit = (s >> (7 - q)) & 1;
        float2 v; v.x = bit ? a1r : a0r; v.y = bit ? a1i : a0i;
        P = cmul(P, v);
    }
    // reg part: qubits 0..3 -> r bits 3..0
    float2 w0[4], w1[4];
#pragma unroll
    for (int k = 0; k < 4; ++k) {
        const int src = (g << 4) + k;
        w0[k].x = __shfl(u0r, src, 64);  w0[k].y = __shfl(u0i, src, 64);
        w1[k].x = __shfl(u1r, src, 64);  w1[k].y = __shfl(u1i, src, 64);
    }
    float2 a[16];
    {
        // doubling over r bits 3,2,1,0 (qubits 0,1,2,3)
        float2 t1[2];
        t1[0] = w0[0];
        t1[1] = w1[0];
        float2 t2[4];
#pragma unroll
        for (int h = 0; h < 2; ++h) {
            t2[h * 2 + 0] = cmul(t1[h], w0[1]);
            t2[h * 2 + 1] = cmul(t1[h], w1[1]);
        }
        float2 t3[8];
#pragma unroll
        for (int h = 0; h < 4; ++h) {
            t3[h * 2 + 0] = cmul(t2[h], w0[2]);
            t3[h * 2 + 1] = cmul(t2[h], w1[2]);
        }
#pragma unroll
        for (int h = 0; h < 8; ++h) {
            a[h * 2 + 0] = cmul(P, cmul(t3[h], w0[3]));
            a[h * 2 + 1] = cmul(P, cmul(t3[h], w1[3]));
        }
    }

    // ---- CRZ ring fused into one diagonal phase per amp (L1 bit mapping) ----
    // idx-bit pairs: (7,6,w0)(6,5,w1)(5,4,w2)(4,3,w3)(3,2,w4)(2,1,w5)(1,0,w6)(0,7,w7)
    // L1: bits 7..4 = r bits 3..0 ; bits 3..0 = s bits 3..0.
    {
        const float wv0 = W[0], wv1 = W[1], wv2 = W[2], wv3 = W[3];
        const float wv4 = W[4], wv5 = W[5], wv6 = W[6], wv7 = W[7];
        const int s3 = (s >> 3) & 1, s2 = (s >> 2) & 1, s1 = (s >> 1) & 1, s0 = s & 1;
        float phiS = 0.0f;
        phiS += s3 ? (s2 ? wv4 : -wv4) : 0.0f;
        phiS += s2 ? (s1 ? wv5 : -wv5) : 0.0f;
        phiS += s1 ? (s0 ? wv6 : -wv6) : 0.0f;
        const float termA = s3 ? wv3 : -wv3;   // pair (4,3): ctrl r0, sign by s3
        const float termB = s0 ? wv7 : 0.0f;   // pair (0,7): ctrl s0, sign by r3
#pragma unroll
        for (int r = 0; r < 16; ++r) {
            const int b3 = (r >> 3) & 1, b2 = (r >> 2) & 1, b1 = (r >> 1) & 1, b0 = r & 1;
            float phi = phiS + (b3 ? termB : -termB);
            if (b3) phi += b2 ? wv0 : -wv0;
            if (b2) phi += b1 ? wv1 : -wv1;
            if (b1) phi += b0 ? wv2 : -wv2;
            if (b0) phi += termA;
            float2 ph;
            __sincosf(0.5f * phi, &ph.y, &ph.x);
            a[r] = cmul(a[r], ph);
        }
    }

    // ---- CRX phase A: groups i=0..3 in L1 (ctrl = reg bit 3-i) ----
#pragma unroll
    for (int i = 0; i < 4; ++i) {
        float cg[8], sg[8];
#pragma unroll
        for (int j = 0; j < 8; ++j) {
            if (j == i) continue;
            const int gi = i * 7 + (j < i ? j : j - 1);
            cg[j] = rlane(gcv, gi);
            sg[j] = rlane(gsv, gi);
        }
        const int rc = 3 - i;
#pragma unroll
        for (int j = 0; j < 8; ++j) {
            if (j == i) continue;
            if (j < 4) {  // reg target bit (3-j): pair update on ctrl=1 regs
                const int mt = 1 << (3 - j);
#pragma unroll
                for (int r = 0; r < 16; ++r) {
                    if (!((r >> rc) & 1)) continue;
                    if (r & mt) continue;
                    const int rp = r | mt;
                    const float2 t = a[r], u = a[rp];
                    a[r]  = rotA(t, u, cg[j], sg[j]);
                    a[rp] = rotA(u, t, cg[j], sg[j]);
                }
            } else {      // lane target: s bit (7-j) -> DPP xor(1<<(7-j))
                const int ms = 1 << (7 - j);
#pragma unroll
                for (int r = 0; r < 16; ++r) {
                    if (!((r >> rc) & 1)) continue;
                    const float2 p = xorM2(a[r], ms);
                    a[r] = rotA(a[r], p, cg[j], sg[j]);
                }
            }
        }
    }

    // ---- 16x16 transpose L1 -> L2 via xor-swap stages (k = 1,2,4,8) ----
#pragma unroll
    for (int k = 1; k <= 8; k <<= 1) {
        const bool sk = (s & k) != 0;
#pragma unroll
        for (int r = 0; r < 16; ++r) {
            if (r & k) continue;
            const int rp = r | k;
            const float2 tp = xorM2(a[rp], k);
            const float2 tr = xorM2(a[r],  k);
            a[r].x  = sk ? tp.x : a[r].x;
            a[r].y  = sk ? tp.y : a[r].y;
            a[rp].x = sk ? a[rp].x : tr.x;
            a[rp].y = sk ? a[rp].y : tr.y;
        }
    }

    // ---- CRX phase B: groups i=4..7 in L2 (ctrl = reg bit 7-i) ----
#pragma unroll
    for (int i = 4; i < 8; ++i) {
        float cg[8], sg[8];
#pragma unroll
        for (int j = 0; j < 8; ++j) {
            if (j == i) continue;
            const int gi = i * 7 + (j < i ? j : j - 1);
            cg[j] = rlane(gcv, gi);
            sg[j] = rlane(gsv, gi);
        }
        const int rc = 7 - i;
#pragma unroll
        for (int j = 0; j < 8; ++j) {
            if (j == i) continue;
            if (j < 4) {  // lane target: s bit (3-j) -> DPP xor(1<<(3-j))
                const int ms = 1 << (3 - j);
#pragma unroll
                for (int r = 0; r < 16; ++r) {
                    if (!((r >> rc) & 1)) continue;
                    const float2 p = xorM2(a[r], ms);
                    a[r] = rotA(a[r], p, cg[j], sg[j]);
                }
            } else {      // reg target bit (7-j)
                const int mt = 1 << (7 - j);
#pragma unroll
                for (int r = 0; r < 16; ++r) {
                    if (!((r >> rc) & 1)) continue;
                    if (r & mt) continue;
                    const int rp = r | mt;
                    const float2 t = a[r], u = a[rp];
                    a[r]  = rotA(t, u, cg[j], sg[j]);
                    a[rp] = rotA(u, t, cg[j], sg[j]);
                }
            }
        }
    }

    // ---- probabilities + all 8 <Z_q>  (L2: r bits 3..0 = qubits 4..7, s bits 3..0 = q0..q3) ----
    float p[16];
#pragma unroll
    for (int r = 0; r < 16; ++r) p[r] = a[r].x * a[r].x + a[r].y * a[r].y;
    float s8[8], E7 = 0.0f;
#pragma unroll
    for (int k = 0; k < 8; ++k) { s8[k] = p[2 * k] + p[2 * k + 1]; E7 += p[2 * k] - p[2 * k + 1]; }
    float s4[4], E6 = 0.0f;
#pragma unroll
    for (int k = 0; k < 4; ++k) { s4[k] = s8[2 * k] + s8[2 * k + 1]; E6 += s8[2 * k] - s8[2 * k + 1]; }
    float s2a[2], E5 = 0.0f;
#pragma unroll
    for (int k = 0; k < 2; ++k) { s2a[k] = s4[2 * k] + s4[2 * k + 1]; E5 += s4[2 * k] - s4[2 * k + 1]; }
    float A  = s2a[0] + s2a[1];
    float E4 = s2a[0] - s2a[1];
    float D0, D1, D2, D3;
    { const float t = xor1f(A); D0 = A - t; A += t;
      E4 += xor1f(E4); E5 += xor1f(E5); E6 += xor1f(E6); E7 += xor1f(E7); }
    { const float t = xor2f(A); D1 = A - t; A += t;
      D0 += xor2f(D0);
      E4 += xor2f(E4); E5 += xor2f(E5); E6 += xor2f(E6); E7 += xor2f(E7); }
    { const float t = xor4f(A); D2 = A - t; A += t;
      D0 += xor4f(D0); D1 += xor4f(D1);
      E4 += xor4f(E4); E5 += xor4f(E5); E6 += xor4f(E6); E7 += xor4f(E7); }
    { const float t = xor8f(A); D3 = A - t;
      D0 += xor8f(D0); D1 += xor8f(D1); D2 += xor8f(D2);
      E4 += xor8f(E4); E5 += xor8f(E5); E6 += xor8f(E6); E7 += xor8f(E7); }

    if (s == 0 && active) {
        const float sc = 1.0f / 256.0f;  // (1/sqrt2)^8 squared, folded out of u's
        float* o = out + b * 8;
        o[0] = D3 * sc;
        o[1] = D2 * sc;
        o[2] = D1 * sc;
        o[3] = D0 * sc;
        o[4] = E4 * sc;
        o[5] = E5 * sc;
        o[6] = E6 * sc;
        o[7] = E7 * sc;
    }
}

extern "C" void kernel_launch(void* const* d_in, const int* in_sizes, int n_in,
                              void* d_out, int out_size, void* d_ws, size_t ws_size,
                              hipStream_t stream) {
    const float* X = (const float*)d_in[0];
    const float* W = (const float*)d_in[1];
    float* out = (float*)d_out;
    const int B = in_sizes[0] / 16;       // 2*N floats per row
    const int blocks = (B + 63) / 64;     // 16 waves x 4 elements per 1024-thread block
    qsim_kernel<<<blocks, 1024, 0, stream>>>(X, W, out, B);
}